// Round 4
// baseline (420.240 us; speedup 1.0000x reference)
//
#include <hip/hip_runtime.h>

// Round 3: two-pass row binning -> every output cache line written exactly once.
//   Pass 1: bin (col,val) entries per output row in d_ws (atomicAdd counts).
//   Pass 2: one workgroup per row: zero LDS row, scatter bucket entries into
//           LDS, set diagonal, stream row to d_out with coalesced float4.
//   Eliminates: standalone 256MB zero-fill + 3.2M random RMW line dirties.
// Fallback (ws too small): R2 fill+scatter path.

typedef float f4 __attribute__((ext_vector_type(4)));

// ---------------- two-pass path ----------------

__global__ __launch_bounds__(256) void zero_counts_kernel(
    unsigned int* __restrict__ counts, int d)
{
    int t = blockIdx.x * blockDim.x + threadIdx.x;
    if (t < d) counts[t] = 0u;
}

__global__ __launch_bounds__(256) void bin_kernel(
    const int* __restrict__ idx,          // [2, M]
    const float* __restrict__ vals,       // [M]
    unsigned int* __restrict__ counts,    // [D]
    uint2* __restrict__ buckets,          // [D][cap]  {col, valbits}
    float scale,
    int m,
    int cap)
{
    int k = blockIdx.x * blockDim.x + threadIdx.x;
    if (k >= m) return;
    int i = idx[k];
    int j = idx[m + k];
    float v = vals[k] * scale;
    unsigned int vb = __float_as_uint(v);
    unsigned int p1 = atomicAdd(&counts[i], 1u);
    buckets[(long long)i * cap + p1] = make_uint2((unsigned)j, vb);
    unsigned int p2 = atomicAdd(&counts[j], 1u);
    buckets[(long long)j * cap + p2] = make_uint2((unsigned)i, vb);
}

__global__ __launch_bounds__(256) void build_rows_kernel(
    float* __restrict__ out,
    const unsigned int* __restrict__ counts,
    const uint2* __restrict__ buckets,
    const float* __restrict__ h_local,
    int d,        // 8192
    int logd,
    int cap)
{
    __shared__ float row[8192];           // 32 KB
    const int r   = blockIdx.x;
    const int tid = threadIdx.x;

    // zero the LDS row: 8192 floats = 2048 float4, 256 threads x 8
    f4* rowv = (f4*)row;
    #pragma unroll
    for (int it = 0; it < 8; ++it) {
        f4 z = {0.f, 0.f, 0.f, 0.f};
        rowv[it * 256 + tid] = z;
    }
    __syncthreads();

    // scatter this row's entries into LDS
    const unsigned int cnt = counts[r];
    const uint2* b = buckets + (long long)r * cap;
    for (unsigned int t = tid; t < cnt; t += 256) {
        uint2 e = b[t];
        row[e.x] = __uint_as_float(e.y);
    }
    if (tid == 0) row[r] = h_local[r];
    __syncthreads();

    // stream the finished row to global: coalesced float4
    f4* outv = (f4*)(out + ((long long)r << logd));
    #pragma unroll
    for (int it = 0; it < 8; ++it) {
        outv[it * 256 + tid] = rowv[it * 256 + tid];
    }
}

// ---------------- fallback path (R2) ----------------

__global__ __launch_bounds__(256) void zero_fill_kernel(
    f4* __restrict__ out, long long n4)
{
    long long t = (long long)blockIdx.x * blockDim.x + threadIdx.x;
    if (t < n4) {
        f4 z = {0.f, 0.f, 0.f, 0.f};
        out[t] = z;
    }
}

__global__ __launch_bounds__(256) void scatter_kernel(
    float* __restrict__ out,
    const int* __restrict__ idx,
    const float* __restrict__ vals,
    const float* __restrict__ h_local,
    float scale, int m, int d, int logd)
{
    int k = blockIdx.x * blockDim.x + threadIdx.x;
    if (k >= m) return;
    int i = idx[k];
    int j = idx[m + k];
    float v = vals[k] * scale;
    out[((long long)i << logd) + j] = v;
    out[((long long)j << logd) + i] = v;
    if (k < d) out[((long long)k << logd) + k] = h_local[k];
}

extern "C" void kernel_launch(void* const* d_in, const int* in_sizes, int n_in,
                              void* d_out, int out_size, void* d_ws, size_t ws_size,
                              hipStream_t stream) {
    const float* h_local = (const float*)d_in[0];
    const float* V_int   = (const float*)d_in[1];
    const int*   idx     = (const int*)d_in[2];

    const int d = in_sizes[0];            // 8192
    const int m = in_sizes[1];            // 1,600,000

    int logd = 0;
    while ((1 << logd) < d) ++logd;

    const double iscale_d = 1.0 - 0.2 / sqrt(log((double)d));
    const float  iscale   = (float)iscale_d;

    float* out = (float*)d_out;
    const int block = 256;

    // Workspace layout: counts (d x u32, padded to 4KB) | buckets (d x cap x 8B)
    const size_t counts_bytes = ((size_t)d * 4 + 4095) & ~(size_t)4095;
    int cap = 0;
    if (ws_size > counts_bytes) {
        size_t avail = ws_size - counts_bytes;
        size_t c = avail / ((size_t)d * 8);
        cap = (int)(c > 1024 ? 1024 : c);
    }

    if (cap >= 512 && d == 8192) {
        // Two-pass binning path.
        unsigned int* counts = (unsigned int*)d_ws;
        uint2* buckets = (uint2*)((char*)d_ws + counts_bytes);

        zero_counts_kernel<<<(d + block - 1) / block, block, 0, stream>>>(counts, d);
        bin_kernel<<<(m + block - 1) / block, block, 0, stream>>>(
            idx, V_int, counts, buckets, iscale, m, cap);
        build_rows_kernel<<<d, block, 0, stream>>>(
            out, counts, buckets, h_local, d, logd, cap);
    } else {
        // Fallback: fill + scatter (R2).
        const long long n4 = ((long long)d * d) >> 2;
        const long long grid_fill = (n4 + block - 1) / block;
        zero_fill_kernel<<<(dim3)(unsigned)grid_fill, block, 0, stream>>>((f4*)out, n4);
        const int grid_sc = (m + block - 1) / block;
        scatter_kernel<<<grid_sc, block, 0, stream>>>(out, idx, V_int, h_local,
                                                      iscale, m, d, logd);
    }
}

// Round 5
// 381.839 us; speedup vs baseline: 1.1006x; 1.1006x over previous
//
#include <hip/hip_runtime.h>

// Round 4: back to the R2 two-kernel structure (our best: 364 us), tuned.
//   Accounting across R0-R4 says ~280 us of dur_us is harness re-poison
//   (1 GB d_ws + 256 MB d_out memsets) -- controllable kernel time is only
//   ~70-90 us: fill ~55 + scatter ~25. This round squeezes those:
//   - fill: 1024-thr blocks, grid-stride x4, 64 B/thread streaming stores
//   - scatter: grid-stride x2 (half the waves), diag folded in
//   R3 lesson: binning relocates the 3.2M random stores, doesn't remove them.
//   R1 lesson: keep fill CACHED so scatter RMWs hit L3, not cold HBM.

typedef float f4 __attribute__((ext_vector_type(4)));

__global__ __launch_bounds__(1024) void zero_fill_kernel(
    f4* __restrict__ out, unsigned n4)
{
    unsigned t = blockIdx.x * 1024u + threadIdx.x;
    unsigned stride = gridDim.x * 1024u;
    f4 z = {0.f, 0.f, 0.f, 0.f};
    for (unsigned p = t; p < n4; p += stride) {
        out[p] = z;
    }
}

__global__ __launch_bounds__(256) void scatter_kernel(
    float* __restrict__ out,
    const int* __restrict__ idx,          // [2, M] int32: row 0 = i, row 1 = j
    const float* __restrict__ vals,       // [M]
    const float* __restrict__ h_local,    // [D]
    float scale,
    int m,
    int d,
    int logd,
    int T)                                // total threads (grid stride)
{
    int t = blockIdx.x * 256 + threadIdx.x;
    for (int k = t; k < m; k += T) {
        int i = idx[k];
        int j = idx[m + k];
        float v = vals[k] * scale;
        out[((long long)i << logd) + j] = v;
        out[((long long)j << logd) + i] = v;
    }
    // Diagonal: first d threads (T >= d guaranteed by launcher). Unscaled.
    if (t < d) {
        out[((long long)t << logd) + t] = h_local[t];
    }
}

extern "C" void kernel_launch(void* const* d_in, const int* in_sizes, int n_in,
                              void* d_out, int out_size, void* d_ws, size_t ws_size,
                              hipStream_t stream) {
    const float* h_local = (const float*)d_in[0];
    const float* V_int   = (const float*)d_in[1];
    const int*   idx     = (const int*)d_in[2];

    const int d = in_sizes[0];            // 8192
    const int m = in_sizes[1];            // 1,600,000

    int logd = 0;
    while ((1 << logd) < d) ++logd;

    const double iscale_d = 1.0 - 0.2 / sqrt(log((double)d));
    const float  iscale   = (float)iscale_d;

    float* out = (float*)d_out;

    // Kernel 1: streaming zero fill. n4 = D*D/4 float4 chunks; 4 chunks/thread.
    const unsigned n4 = (unsigned)(((long long)d * d) >> 2);   // 16.7M
    unsigned grid_fill = (n4 + 1024u * 4u - 1u) / (1024u * 4u); // 4096 blocks
    zero_fill_kernel<<<grid_fill, 1024, 0, stream>>>((f4*)out, n4);

    // Kernel 2: symmetric scatter + diagonal, ~2 pairs per thread.
    int T = (m + 1) / 2;
    // round T up to block multiple, and ensure T >= d for the diag writes
    T = ((T + 255) / 256) * 256;
    if (T < d) T = ((d + 255) / 256) * 256;
    const int grid_sc = T / 256;
    scatter_kernel<<<grid_sc, 256, 0, stream>>>(out, idx, V_int, h_local,
                                                iscale, m, d, logd, T);
}

// Round 6
// 373.177 us; speedup vs baseline: 1.1261x; 1.0232x over previous
//
#include <hip/hip_runtime.h>

// Round 5: R2 structure restored (our best, 364 us), fill micro-tuned.
//   - scatter: EXACTLY R2's 1-pair-per-thread (R4's grid-stride x2 halved MLP
//     of the latency-bound random stores: +18 us. Reverted.)
//   - fill: 256-thr blocks, each block owns a 32KB contiguous slab, 8 coalesced
//     float4 stores/thread -> 8192 blocks instead of 65536 single-store blocks.
//   Calibration across R0-R4: dur_us carries ~283 us of harness re-poison
//   (1GB ws + 256MB out memsets + input restore); controllable kernel time
//   at R2 was ~81 us (fill ~54 + scatter ~24 + 2 launches).
//   R1 lesson: cached stores only (L3 warmth feeds the scatter RMWs).
//   R3 lesson: no binning - it relocates the 3.2M random stores, not removes.

typedef float f4 __attribute__((ext_vector_type(4)));

__global__ __launch_bounds__(256) void zero_fill_kernel(
    f4* __restrict__ out)
{
    // Block b owns chunks [b*2048, (b+1)*2048): 32KB contiguous.
    // Iteration it: threads write 4KB contiguous (256 x 16B), coalesced.
    f4* base = out + (long long)blockIdx.x * 2048;
    const int tid = threadIdx.x;
    f4 z = {0.f, 0.f, 0.f, 0.f};
    #pragma unroll
    for (int it = 0; it < 8; ++it) {
        base[it * 256 + tid] = z;
    }
}

__global__ __launch_bounds__(256) void scatter_kernel(
    float* __restrict__ out,
    const int* __restrict__ idx,          // [2, M] int32: row 0 = i, row 1 = j
    const float* __restrict__ vals,       // [M]
    const float* __restrict__ h_local,    // [D]
    float scale,
    int m,
    int d,
    int logd)
{
    int k = blockIdx.x * blockDim.x + threadIdx.x;
    if (k >= m) return;
    int i = idx[k];
    int j = idx[m + k];
    float v = vals[k] * scale;
    out[((long long)i << logd) + j] = v;
    out[((long long)j << logd) + i] = v;
    // Diagonal: first d threads (d=8192 << m). Unscaled h_local.
    if (k < d) {
        out[((long long)k << logd) + k] = h_local[k];
    }
}

extern "C" void kernel_launch(void* const* d_in, const int* in_sizes, int n_in,
                              void* d_out, int out_size, void* d_ws, size_t ws_size,
                              hipStream_t stream) {
    const float* h_local = (const float*)d_in[0];
    const float* V_int   = (const float*)d_in[1];
    const int*   idx     = (const int*)d_in[2];

    const int d = in_sizes[0];            // 8192
    const int m = in_sizes[1];            // 1,600,000

    int logd = 0;
    while ((1 << logd) < d) ++logd;

    const double iscale_d = 1.0 - 0.2 / sqrt(log((double)d));
    const float  iscale   = (float)iscale_d;

    float* out = (float*)d_out;
    const int block = 256;

    // Kernel 1: zero fill. D*D floats = D*D/4 chunks; 2048 chunks per block.
    const long long n4 = ((long long)d * d) >> 2;     // 16.7M chunks
    const int grid_fill = (int)(n4 / 2048);           // 8192 blocks (exact: D pow2)
    zero_fill_kernel<<<grid_fill, block, 0, stream>>>((f4*)out);

    // Kernel 2: symmetric scatter + diagonal (stream-ordered after the fill).
    const int grid_sc = (m + block - 1) / block;
    scatter_kernel<<<grid_sc, block, 0, stream>>>(out, idx, V_int, h_local,
                                                  iscale, m, d, logd);
}